// Round 1
// baseline (180.073 us; speedup 1.0000x reference)
//
#include <hip/hip_runtime.h>

#define DIM 64
#define HID 512
#define BATCH 8192
#define SB 16   // samples per block

// P[j][k] = W2[j][k] * sum_i W1[i][j] * W3[k][i]   (512x512), sample-independent
__global__ __launch_bounds__(256) void compute_P(const float* __restrict__ W1,
                                                 const float* __restrict__ W2,
                                                 const float* __restrict__ W3,
                                                 float* __restrict__ P) {
    int idx = blockIdx.x * 256 + threadIdx.x;   // 512*512 elements
    int k = idx & (HID - 1);
    int j = idx >> 9;
    float acc = 0.f;
#pragma unroll
    for (int i = 0; i < DIM; ++i) {
        acc = fmaf(W1[i * HID + j], W3[k * DIM + i], acc);
    }
    P[j * HID + k] = W2[j * HID + k] * acc;
}

__global__ __launch_bounds__(256) void fused_main(
        const float* __restrict__ t,
        const float* __restrict__ x,
        const float* __restrict__ W1, const float* __restrict__ b1,
        const float* __restrict__ W2, const float* __restrict__ b2,
        const float* __restrict__ W3, const float* __restrict__ b3,
        const float* __restrict__ P, float* __restrict__ out) {
    __shared__ float xs[SB][DIM + 1];
    __shared__ float h1s[SB][HID];   // reused for h2 later
    __shared__ float wred[4][SB];

    const int tid = threadIdx.x;
    const int s0 = blockIdx.x * SB;

    // ---- load x tile (+ t as the 65th feature) ----
    for (int l = tid; l < SB * DIM; l += 256) {
        int s = l >> 6, i = l & 63;
        xs[s][i] = x[(s0 + s) * DIM + i];
    }
    if (tid < SB) xs[tid][DIM] = t[0];
    __syncthreads();

    const int k0 = tid, k1 = tid + 256;

    // ---- phase 1: z1 = [x,t] @ W1 + b1 ; h1 = tanh(z1) ----
    float za[SB], zb[SB];
    {
        float ba = b1[k0], bb = b1[k1];
#pragma unroll
        for (int s = 0; s < SB; ++s) { za[s] = ba; zb[s] = bb; }
    }
    for (int i = 0; i <= DIM; ++i) {
        float wa = W1[i * HID + k0], wb = W1[i * HID + k1];
#pragma unroll
        for (int s = 0; s < SB; ++s) {
            float xv = xs[s][i];
            za[s] = fmaf(xv, wa, za[s]);
            zb[s] = fmaf(xv, wb, zb[s]);
        }
    }
#pragma unroll
    for (int s = 0; s < SB; ++s) {
        h1s[s][k0] = tanhf(za[s]);
        h1s[s][k1] = tanhf(zb[s]);
    }
    __syncthreads();

    // ---- phase 2: z2 = h1 @ W2 + b2  and  srow = d1 @ P  (fused) ----
    float sa[SB], sb_[SB];
    {
        float ba = b2[k0], bb = b2[k1];
#pragma unroll
        for (int s = 0; s < SB; ++s) { za[s] = ba; zb[s] = bb; sa[s] = 0.f; sb_[s] = 0.f; }
    }
    for (int j = 0; j < HID; ++j) {
        float w2a = W2[j * HID + k0], w2b = W2[j * HID + k1];
        float pa  = P[j * HID + k0],  pb  = P[j * HID + k1];
#pragma unroll
        for (int s = 0; s < SB; ++s) {
            float h = h1s[s][j];           // LDS broadcast (uniform addr)
            float d = fmaf(-h, h, 1.0f);   // d1 recomputed, saves 32KB LDS
            za[s]  = fmaf(h, w2a, za[s]);
            zb[s]  = fmaf(h, w2b, zb[s]);
            sa[s]  = fmaf(d, pa, sa[s]);
            sb_[s] = fmaf(d, pb, sb_[s]);
        }
    }

    // ---- h2, d2, per-thread divergence partials ----
    float divp[SB];
#pragma unroll
    for (int s = 0; s < SB; ++s) {
        float h2a = tanhf(za[s]), h2b = tanhf(zb[s]);
        float d2a = fmaf(-h2a, h2a, 1.0f), d2b = fmaf(-h2b, h2b, 1.0f);
        divp[s] = fmaf(sa[s], d2a, sb_[s] * d2b);
        za[s] = h2a; zb[s] = h2b;
    }
    __syncthreads();   // all phase-2 reads of h1s done
#pragma unroll
    for (int s = 0; s < SB; ++s) { h1s[s][k0] = za[s]; h1s[s][k1] = zb[s]; }

    // ---- divergence reduction: wave shuffle, then cross-wave via LDS ----
#pragma unroll
    for (int s = 0; s < SB; ++s) {
        float v = divp[s];
#pragma unroll
        for (int off = 32; off > 0; off >>= 1) v += __shfl_xor(v, off, 64);
        if ((tid & 63) == 0) wred[tid >> 6][s] = v;
    }
    __syncthreads();   // covers h2 writes + wred writes
    if (tid < SB) {
        float d = wred[0][tid] + wred[1][tid] + wred[2][tid] + wred[3][tid];
        out[BATCH * DIM + s0 + tid] = -d;
    }

    // ---- phase 3: v = h2 @ W3 + b3 ----
    const int o = tid & 63, sg = tid >> 6;
    float acc[4];
    float b3o = b3[o];
#pragma unroll
    for (int m = 0; m < 4; ++m) acc[m] = b3o;
    for (int k = 0; k < HID; ++k) {
        float w3 = W3[k * DIM + o];
#pragma unroll
        for (int m = 0; m < 4; ++m) acc[m] = fmaf(h1s[sg * 4 + m][k], w3, acc[m]);
    }
#pragma unroll
    for (int m = 0; m < 4; ++m) out[(s0 + sg * 4 + m) * DIM + o] = acc[m];
}

extern "C" void kernel_launch(void* const* d_in, const int* in_sizes, int n_in,
                              void* d_out, int out_size, void* d_ws, size_t ws_size,
                              hipStream_t stream) {
    const float* t  = (const float*)d_in[0];
    const float* x  = (const float*)d_in[1];
    const float* W1 = (const float*)d_in[2];
    const float* b1 = (const float*)d_in[3];
    const float* W2 = (const float*)d_in[4];
    const float* b2 = (const float*)d_in[5];
    const float* W3 = (const float*)d_in[6];
    const float* b3 = (const float*)d_in[7];
    float* out = (float*)d_out;
    float* P   = (float*)d_ws;   // 512*512*4 = 1 MB

    compute_P<<<(HID * HID) / 256, 256, 0, stream>>>(W1, W2, W3, P);
    fused_main<<<BATCH / SB, 256, 0, stream>>>(t, x, W1, b1, W2, b2, W3, b3, P, out);
}